// Round 2
// baseline (126.774 us; speedup 1.0000x reference)
//
#include <hip/hip_runtime.h>

// MCGRU: 64 independent hidden-8 GRUs scanned over the batch axis (4096 steps),
// parallelized via contraction burn-in chunking (16 chunks x 256 + 256 warmup).
// Kernel 1: last_T[l][b] = (x[:, -1, :] @ W_lab + b_lab)^T
// Kernel 2: GRU scan, one wave per (lab, chunk); cross-lane via DPP + shfl_xor.
// Kernel 3: out = concat(demo, feat) @ W_out + b_out (demo fused).

#define TSTRIDE  4112   // 4096 + 16 pad (prefetch overrun safety)
#define NCHUNK   16
#define CHUNKLEN 256
#define WARM     256

__device__ __forceinline__ float f_exp2(float x){ return __builtin_amdgcn_exp2f(x); }
__device__ __forceinline__ float f_rcp (float x){ return __builtin_amdgcn_rcpf(x); }

template<int CTRL>
__device__ __forceinline__ float dpp_mov(float v){
  return __int_as_float(__builtin_amdgcn_update_dpp(0, __float_as_int(v), CTRL, 0xF, 0xF, true));
}

// reduce over lane bits {3,4,5} (masks 8,16,32); result replicated to all lanes
__device__ __forceinline__ void reduceA(float &v){
  v += dpp_mov<0x128>(v);     // row_ror:8 == xor8 within 16-lane row
  v += __shfl_xor(v, 16);     // xor16 (ds_bpermute path, guaranteed semantics)
  v += __shfl_xor(v, 32);     // xor32
}
// reduce over lane bits {0,1,2} (masks 1,2,then 7 which ≡ 4 after stage 2)
__device__ __forceinline__ void reduceB(float &v){
  v += dpp_mov<0xB1>(v);      // quad_perm [1,0,3,2] == xor1
  v += dpp_mov<0x4E>(v);      // quad_perm [2,3,0,1] == xor2
  v += dpp_mov<0x141>(v);     // row_half_mirror == xor7 ≡ xor4 here (value depends only on lane>>2)
}

// ---------------- kernel 1: last_T ----------------
__global__ __launch_bounds__(256) void lastT_kernel(
    const float* __restrict__ x,      // [4096][128][64]
    const float* __restrict__ W_lab,  // [64][64]
    const float* __restrict__ b_lab,  // [64]
    float* __restrict__ lastT)        // [64][TSTRIDE]
{
  const int lane = threadIdx.x & 63;
  const int w    = __builtin_amdgcn_readfirstlane(threadIdx.x >> 6); // wave 0..3 (uniform)
  const int b    = blockIdx.x * 64 + lane;

  // defensive: zero the prefetch pad region (block 0 only)
  if (blockIdx.x == 0) {
    for (int p = threadIdx.x; p < 64 * 16; p += 256) {
      lastT[(p >> 4) * TSTRIDE + 4096 + (p & 15)] = 0.0f;
    }
  }

  float xv[64];
  const float4* xr = (const float4*)(x + ((size_t)b*128 + 127)*64);
  #pragma unroll
  for (int i = 0; i < 16; ++i) ((float4*)xv)[i] = xr[i];
  for (int li = 0; li < 16; ++li) {
    const int l = w*16 + li;            // uniform per wave -> scalar W loads
    float acc = b_lab[l];
    #pragma unroll
    for (int k = 0; k < 64; ++k)
      acc = fmaf(xv[k], W_lab[k*64 + l], acc);
    lastT[l*TSTRIDE + b] = acc;         // coalesced (lanes = consecutive b)
  }
}

// ---------------- kernel 2: GRU scan ----------------
__global__ __launch_bounds__(64) void gru_kernel(
    const float* __restrict__ lastT,  // [64][TSTRIDE]
    const float* __restrict__ W_ih,   // [64][24]
    const float* __restrict__ W_hh,   // [64][24][8]
    const float* __restrict__ b_ih,   // [64][24]
    const float* __restrict__ b_hh,   // [64][24]
    float* __restrict__ feat)         // [4096][512]
{
  const int lane = threadIdx.x;       // 0..63
  const int l = blockIdx.x >> 4;      // lab
  const int c = blockIdx.x & 15;      // chunk
  const int uA = lane & 7, jA = lane >> 3;
  const int uB = jA,       jB = uA;

  const float LOG2E = 1.4426950408889634f;
  const float c_rz = -LOG2E;          // sigmoid: 1/(1+exp2(-log2e*s))
  const float c_n  = 2.0f*LOG2E;      // tanh:    1-2/(1+exp2(2*log2e*t))

  const float* Whh = W_hh + l*192;
  const float* Wih = W_ih + l*24;
  const float* bih = b_ih + l*24;
  const float* bhh = b_hh + l*24;

  // parity A constants (lane role: h-index jA, output unit uA)
  const float wAr  = c_rz * Whh[(0 +uA)*8 + jA];
  const float wAz  = c_rz * Whh[(8 +uA)*8 + jA];
  const float wAn  = c_n  * Whh[(16+uA)*8 + jA];
  const float wiAr = c_rz * Wih[uA],     bAr = c_rz*(bih[uA]    + bhh[uA]);
  const float wiAz = c_rz * Wih[8+uA],   bAz = c_rz*(bih[8+uA]  + bhh[8+uA]);
  const float wiAn = c_n  * Wih[16+uA],  bAn = c_n * bih[16+uA];
  const float bhAn = c_n  * bhh[16+uA];
  // parity B constants (roles transposed)
  const float wBr  = c_rz * Whh[(0 +uB)*8 + jB];
  const float wBz  = c_rz * Whh[(8 +uB)*8 + jB];
  const float wBn  = c_n  * Whh[(16+uB)*8 + jB];
  const float wiBr = c_rz * Wih[uB],     bBr = c_rz*(bih[uB]    + bhh[uB]);
  const float wiBz = c_rz * Wih[8+uB],   bBz = c_rz*(bih[8+uB]  + bhh[8+uB]);
  const float wiBn = c_n  * Wih[16+uB],  bBn = c_n * bih[16+uB];
  const float bhBn = c_n  * bhh[16+uB];

  const float sel = (uA == jA) ? 1.0f : 0.0f;  // diagonal: h passthrough channel

  const int nwarm  = (c == 0) ? 0 : WARM;
  const int base   = c*CHUNKLEN - nwarm;
  const int nsteps = CHUNKLEN + nwarm;

  const float2* xs2 = (const float2*)(lastT + (size_t)l*TSTRIDE + base);
  float2 xcur = xs2[0];
  float2 xnxt = xs2[1];

  float* fA = feat + l*8 + uA;   // store lanes: jA==0 (lanes 0..7)
  float* fB = feat + l*8 + uB;   // store lanes: jB==0 (lanes 0,8,..,56)

  float h = 0.0f;
  for (int s = 0; s < nsteps; s += 2) {
    float2 xpf = xs2[(s >> 1) + 2];  // prefetch 2 iterations ahead (pad covers tail)
    // ---- step A: h indexed by jA (bits 3-5); reduce over bits {3,4,5} ----
    {
      float pr = wAr*h, pz = wAz*h, pn = wAn*h, ph = sel*h;
      reduceA(pr); reduceA(pz); reduceA(pn); reduceA(ph);
      float gir = fmaf(xcur.x, wiAr, bAr);
      float giz = fmaf(xcur.x, wiAz, bAz);
      float gin = fmaf(xcur.x, wiAn, bAn);
      float r  = f_rcp(1.0f + f_exp2(pr + gir));
      float z  = f_rcp(1.0f + f_exp2(pz + giz));
      float t2 = fmaf(r, pn + bhAn, gin);
      float n  = fmaf(-2.0f, f_rcp(1.0f + f_exp2(t2)), 1.0f);
      h = fmaf(z, ph - n, n);                      // (1-z)n + z*h_old[u]
      if (s >= nwarm && jA == 0) fA[(size_t)(base + s)*512] = h;
    }
    // ---- step B: h indexed by uA==jB (bits 0-2); reduce over bits {0,1,2} ----
    {
      float pr = wBr*h, pz = wBz*h, pn = wBn*h, ph = sel*h;
      reduceB(pr); reduceB(pz); reduceB(pn); reduceB(ph);
      float gir = fmaf(xcur.y, wiBr, bBr);
      float giz = fmaf(xcur.y, wiBz, bBz);
      float gin = fmaf(xcur.y, wiBn, bBn);
      float r  = f_rcp(1.0f + f_exp2(pr + gir));
      float z  = f_rcp(1.0f + f_exp2(pz + giz));
      float t2 = fmaf(r, pn + bhBn, gin);
      float n  = fmaf(-2.0f, f_rcp(1.0f + f_exp2(t2)), 1.0f);
      h = fmaf(z, ph - n, n);
      if (s + 1 >= nwarm && jB == 0) fB[(size_t)(base + s + 1)*512] = h;
    }
    xcur = xnxt; xnxt = xpf;
  }
}

// ---------------- kernel 3: output GEMM ----------------
__global__ __launch_bounds__(256) void out_kernel(
    const float* __restrict__ statik, // [4096][16]
    const float* __restrict__ W_demo, // [16][32]
    const float* __restrict__ b_demo, // [32]
    const float* __restrict__ W_out,  // [544][32]
    const float* __restrict__ b_out,  // [32]
    const float* __restrict__ feat,   // [4096][512]
    float* __restrict__ out)          // [4096][32]
{
  __shared__ float demo_s[8][33];
  const int o  = threadIdx.x & 31;
  const int bl = threadIdx.x >> 5;
  const int b  = blockIdx.x * 8 + bl;

  float d = b_demo[o];
  const float* sb = statik + (size_t)b*16;
  #pragma unroll
  for (int q = 0; q < 16; ++q) d = fmaf(sb[q], W_demo[q*32 + o], d);
  demo_s[bl][o] = d;
  __syncthreads();

  float acc = b_out[o];
  #pragma unroll
  for (int m = 0; m < 32; ++m) acc = fmaf(demo_s[bl][m], W_out[m*32 + o], acc);

  const float* fb = feat + (size_t)b*512;
  const float* Wf = W_out + 1024 + o;   // rows 32.. (feat part), index k*32
  for (int k = 0; k < 512; k += 8) {
    float4 f0 = *(const float4*)(fb + k);
    float4 f1 = *(const float4*)(fb + k + 4);
    acc = fmaf(f0.x, Wf[(k+0)*32], acc);
    acc = fmaf(f0.y, Wf[(k+1)*32], acc);
    acc = fmaf(f0.z, Wf[(k+2)*32], acc);
    acc = fmaf(f0.w, Wf[(k+3)*32], acc);
    acc = fmaf(f1.x, Wf[(k+4)*32], acc);
    acc = fmaf(f1.y, Wf[(k+5)*32], acc);
    acc = fmaf(f1.z, Wf[(k+6)*32], acc);
    acc = fmaf(f1.w, Wf[(k+7)*32], acc);
  }
  out[(size_t)b*32 + o] = acc;
}

extern "C" void kernel_launch(void* const* d_in, const int* in_sizes, int n_in,
                              void* d_out, int out_size, void* d_ws, size_t ws_size,
                              hipStream_t stream) {
  const float* x      = (const float*)d_in[0];
  const float* statik = (const float*)d_in[1];
  const float* W_demo = (const float*)d_in[2];
  const float* b_demo = (const float*)d_in[3];
  const float* W_lab  = (const float*)d_in[4];
  const float* b_lab  = (const float*)d_in[5];
  const float* W_ih   = (const float*)d_in[6];
  const float* W_hh   = (const float*)d_in[7];
  const float* b_ih   = (const float*)d_in[8];
  const float* b_hh   = (const float*)d_in[9];
  const float* W_out  = (const float*)d_in[10];
  const float* b_out  = (const float*)d_in[11];
  float* out = (float*)d_out;

  float* lastT = (float*)d_ws;                                 // 64*4112*4 = 1,052,672 B
  float* feat  = (float*)((char*)d_ws + (size_t)64*TSTRIDE*4); // 4096*512*4 = 8,388,608 B

  (void)in_sizes; (void)n_in; (void)out_size; (void)ws_size;

  lastT_kernel<<<64,   256, 0, stream>>>(x, W_lab, b_lab, lastT);
  gru_kernel  <<<1024,  64, 0, stream>>>(lastT, W_ih, W_hh, b_ih, b_hh, feat);
  out_kernel  <<<512,  256, 0, stream>>>(statik, W_demo, b_demo, W_out, b_out, feat, out);
}

// Round 3
// 69.122 us; speedup vs baseline: 1.8341x; 1.8341x over previous
//
#include <hip/hip_runtime.h>

// MCGRU: 64 independent hidden-8 GRUs scanned over the batch axis (4096 steps),
// parallelized via contraction burn-in chunking (32 chunks x 128 + 64 warmup).
// Kernel 2 layout: lane = u*8+j. hu = h[u] (replicated over j), hj = h[j]
// (replicated over u, = bpermute-transpose of hu). Gate matvec = products on
// hj reduced over lane bits {0,1,2} with all-DPP butterflies; z*h_old uses hu
// locally. Exactly ONE ds_bpermute per step on the critical path.

#define TSTRIDE  4112
#define NCHUNK   32
#define CHUNKLEN 128
#define WARM     64

__device__ __forceinline__ float f_exp2(float x){ return __builtin_amdgcn_exp2f(x); }
__device__ __forceinline__ float f_rcp (float x){ return __builtin_amdgcn_rcpf(x); }

template<int CTRL>
__device__ __forceinline__ float dpp_mov(float v){
  return __int_as_float(__builtin_amdgcn_update_dpp(0, __float_as_int(v), CTRL, 0xF, 0xF, true));
}
// reduce over lane bits {0,1,2}: xor1, xor2, then xor7 (== xor4 once uniform in quads)
__device__ __forceinline__ void reduceJ(float &v){
  v += dpp_mov<0xB1>(v);      // quad_perm [1,0,3,2] == xor1
  v += dpp_mov<0x4E>(v);      // quad_perm [2,3,0,1] == xor2
  v += dpp_mov<0x141>(v);     // row_half_mirror == xor7 ≡ xor4 here
}

// ---------------- kernel 1: last_T ----------------
__global__ __launch_bounds__(256) void lastT_kernel(
    const float* __restrict__ x,      // [4096][128][64]
    const float* __restrict__ W_lab,  // [64][64]
    const float* __restrict__ b_lab,  // [64]
    float* __restrict__ lastT)        // [64][TSTRIDE]
{
  const int lane = threadIdx.x & 63;
  const int w    = __builtin_amdgcn_readfirstlane(threadIdx.x >> 6);
  const int b    = blockIdx.x * 64 + lane;
  float xv[64];
  const float4* xr = (const float4*)(x + ((size_t)b*128 + 127)*64);
  #pragma unroll
  for (int i = 0; i < 16; ++i) ((float4*)xv)[i] = xr[i];
  for (int li = 0; li < 16; ++li) {
    const int l = w*16 + li;            // wave-uniform -> scalar W loads
    float acc = b_lab[l];
    #pragma unroll
    for (int k = 0; k < 64; ++k)
      acc = fmaf(xv[k], W_lab[k*64 + l], acc);
    lastT[l*TSTRIDE + b] = acc;
  }
}

// ---------------- kernel 2: GRU scan ----------------
__global__ __launch_bounds__(64) void gru_kernel(
    const float* __restrict__ lastT,  // [64][TSTRIDE]
    const float* __restrict__ W_ih,   // [64][24]
    const float* __restrict__ W_hh,   // [64][24][8]
    const float* __restrict__ b_ih,   // [64][24]
    const float* __restrict__ b_hh,   // [64][24]
    float* __restrict__ feat)         // [4096][512]
{
  const int lane = threadIdx.x;       // 0..63
  const int l = blockIdx.x >> 5;      // lab
  const int c = blockIdx.x & (NCHUNK-1);
  const int u = lane >> 3, j = lane & 7;

  const float LOG2E = 1.4426950408889634f;
  const float c_rz = -LOG2E;          // sigmoid: 1/(1+exp2(-log2e*s))
  const float c_n  = 2.0f*LOG2E;      // tanh:    1-2/(1+exp2(2*log2e*t))

  const float* Whh = W_hh + l*192;
  const float* Wih = W_ih + l*24;
  const float* bih = b_ih + l*24;
  const float* bhh = b_hh + l*24;

  // per-lane constants: gate row u, input column j
  const float wr  = c_rz * Whh[(0 +u)*8 + j];
  const float wz  = c_rz * Whh[(8 +u)*8 + j];
  const float wn  = c_n  * Whh[(16+u)*8 + j];
  const float wir = c_rz * Wih[u],      br = c_rz*(bih[u]    + bhh[u]);
  const float wiz = c_rz * Wih[8+u],    bz = c_rz*(bih[8+u]  + bhh[8+u]);
  const float win = c_n  * Wih[16+u],   bn = c_n * bih[16+u];
  const float bhn = c_n  * bhh[16+u];

  const int tr_addr = (((j << 3) | u) << 2);  // transpose: lane u*8+j <- lane j*8+u

  float hu = 0.0f;   // h[u], replicated over j
  float hj = 0.0f;   // h[j], replicated over u

  auto STEP = [&](float x) {
    float pr = wr*hj, pz = wz*hj, pn = wn*hj;
    reduceJ(pr); reduceJ(pz); reduceJ(pn);
    float gr = fmaf(x, wir, br);
    float gz = fmaf(x, wiz, bz);
    float gn = fmaf(x, win, bn);
    float r  = f_rcp(1.0f + f_exp2(pr + gr));
    float z  = f_rcp(1.0f + f_exp2(pz + gz));
    float t2 = fmaf(r, pn + bhn, gn);
    float n  = fmaf(-2.0f, f_rcp(1.0f + f_exp2(t2)), 1.0f);
    hu = fmaf(z, hu - n, n);            // (1-z)n + z*h_old[u]
    hj = __uint_as_float((unsigned)__builtin_amdgcn_ds_bpermute(
             tr_addr, (int)__float_as_uint(hu)));
  };

  const float* xs = lastT + (size_t)l*TSTRIDE;
  int pos = (c == 0) ? 0 : c*CHUNKLEN - WARM;

  if (c != 0) {                         // 64-step warm-in (truncation ~1e-8)
    float xv = xs[pos + lane];
    #pragma unroll 4
    for (int t = 0; t < 64; ++t) {
      float x = __uint_as_float((unsigned)__builtin_amdgcn_readlane(
                    (int)__float_as_uint(xv), t));
      STEP(x);
    }
    pos += 64;
  }

  float* fbase = feat + l*8 + u;
  for (int blk = 0; blk < CHUNKLEN/64; ++blk) {
    float xv = xs[pos + lane];
    #pragma unroll 4
    for (int t = 0; t < 64; t += 2) {
      float x0 = __uint_as_float((unsigned)__builtin_amdgcn_readlane(
                     (int)__float_as_uint(xv), t));
      float x1 = __uint_as_float((unsigned)__builtin_amdgcn_readlane(
                     (int)__float_as_uint(xv), t + 1));
      STEP(x0);
      float h0 = hu;
      STEP(x1);
      if (j < 2)                        // lanes j=0,1 store steps t, t+1
        fbase[(size_t)(pos + t + j)*512] = (j == 0) ? h0 : hu;
    }
    pos += 64;
  }
}

// ---------------- kernel 3: output GEMM ----------------
__global__ __launch_bounds__(256) void out_kernel(
    const float* __restrict__ statik, // [4096][16]
    const float* __restrict__ W_demo, // [16][32]
    const float* __restrict__ b_demo, // [32]
    const float* __restrict__ W_out,  // [544][32]
    const float* __restrict__ b_out,  // [32]
    const float* __restrict__ feat,   // [4096][512]
    float* __restrict__ out)          // [4096][32]
{
  __shared__ float demo_s[8][33];
  const int o  = threadIdx.x & 31;
  const int bl = threadIdx.x >> 5;
  const int b  = blockIdx.x * 8 + bl;

  float d = b_demo[o];
  const float* sb = statik + (size_t)b*16;
  #pragma unroll
  for (int q = 0; q < 16; ++q) d = fmaf(sb[q], W_demo[q*32 + o], d);
  demo_s[bl][o] = d;
  __syncthreads();

  float acc = b_out[o];
  #pragma unroll
  for (int m = 0; m < 32; ++m) acc = fmaf(demo_s[bl][m], W_out[m*32 + o], acc);

  const float* fb = feat + (size_t)b*512;
  const float* Wf = W_out + 1024 + o;
  for (int k = 0; k < 512; k += 8) {
    float4 f0 = *(const float4*)(fb + k);
    float4 f1 = *(const float4*)(fb + k + 4);
    acc = fmaf(f0.x, Wf[(k+0)*32], acc);
    acc = fmaf(f0.y, Wf[(k+1)*32], acc);
    acc = fmaf(f0.z, Wf[(k+2)*32], acc);
    acc = fmaf(f0.w, Wf[(k+3)*32], acc);
    acc = fmaf(f1.x, Wf[(k+4)*32], acc);
    acc = fmaf(f1.y, Wf[(k+5)*32], acc);
    acc = fmaf(f1.z, Wf[(k+6)*32], acc);
    acc = fmaf(f1.w, Wf[(k+7)*32], acc);
  }
  out[(size_t)b*32 + o] = acc;
}

extern "C" void kernel_launch(void* const* d_in, const int* in_sizes, int n_in,
                              void* d_out, int out_size, void* d_ws, size_t ws_size,
                              hipStream_t stream) {
  const float* x      = (const float*)d_in[0];
  const float* statik = (const float*)d_in[1];
  const float* W_demo = (const float*)d_in[2];
  const float* b_demo = (const float*)d_in[3];
  const float* W_lab  = (const float*)d_in[4];
  const float* b_lab  = (const float*)d_in[5];
  const float* W_ih   = (const float*)d_in[6];
  const float* W_hh   = (const float*)d_in[7];
  const float* b_ih   = (const float*)d_in[8];
  const float* b_hh   = (const float*)d_in[9];
  const float* W_out  = (const float*)d_in[10];
  const float* b_out  = (const float*)d_in[11];
  float* out = (float*)d_out;

  float* lastT = (float*)d_ws;                                 // 64*4112*4 B
  float* feat  = (float*)((char*)d_ws + (size_t)64*TSTRIDE*4); // 4096*512*4 B

  (void)in_sizes; (void)n_in; (void)out_size; (void)ws_size;

  lastT_kernel<<<64,        256, 0, stream>>>(x, W_lab, b_lab, lastT);
  gru_kernel  <<<64*NCHUNK,  64, 0, stream>>>(lastT, W_ih, W_hh, b_ih, b_hh, feat);
  out_kernel  <<<512,       256, 0, stream>>>(statik, W_demo, b_demo, W_out, b_out, feat, out);
}

// Round 4
// 65.620 us; speedup vs baseline: 1.9319x; 1.0534x over previous
//
#include <hip/hip_runtime.h>

// MCGRU: 64 independent hidden-8 GRUs scanned over the batch axis (4096 steps).
// Chunked: 64 chunks/lab x 64 live steps + 32-step contraction warm-in.
// gru_kernel fuses the x[:, -1, :]@W_lab projection (per-wave, SGPR weights).
// Lane layout: lane = u*8+j; hu = h[u] (replicated over j), hj = h[j]
// (bpermute transpose of hu). Gate matvec = products on hj reduced over lane
// bits {0,1,2} with all-DPP butterflies; ONE ds_bpermute per step.

#define NCHUNK   64
#define CHUNKLEN 64
#define WARM     32

__device__ __forceinline__ float f_exp2(float x){ return __builtin_amdgcn_exp2f(x); }
__device__ __forceinline__ float f_rcp (float x){ return __builtin_amdgcn_rcpf(x); }

template<int CTRL>
__device__ __forceinline__ float dpp_mov(float v){
  return __int_as_float(__builtin_amdgcn_update_dpp(0, __float_as_int(v), CTRL, 0xF, 0xF, true));
}
// reduce over lane bits {0,1,2}: xor1, xor2, then xor7 (== xor4 once quad-uniform)
__device__ __forceinline__ void reduceJ(float &v){
  v += dpp_mov<0xB1>(v);      // quad_perm [1,0,3,2] == xor1
  v += dpp_mov<0x4E>(v);      // quad_perm [2,3,0,1] == xor2
  v += dpp_mov<0x141>(v);     // row_half_mirror == xor7 == xor4 here
}
__device__ __forceinline__ float bcast_lane(float v, int t){
  return __uint_as_float((unsigned)__builtin_amdgcn_readlane((int)__float_as_uint(v), t));
}

// ---------------- kernel 1: fused projection + GRU scan ----------------
__global__ __launch_bounds__(256, 4) void gru_kernel(
    const float* __restrict__ x,      // [4096][128][64]
    const float* __restrict__ W_lab,  // [64][64]
    const float* __restrict__ b_lab,  // [64]
    const float* __restrict__ W_ih,   // [64][24]
    const float* __restrict__ W_hh,   // [64][24][8]
    const float* __restrict__ b_ih,   // [64][24]
    const float* __restrict__ b_hh,   // [64][24]
    float* __restrict__ feat)         // [4096][512]
{
  const int lane = threadIdx.x & 63;
  const int wv   = threadIdx.x >> 6;             // wave 0..3
  const int l    = blockIdx.x >> 4;              // lab (uniform per block)
  const int c    = ((blockIdx.x & 15) << 2) | wv; // chunk 0..63
  const int u = lane >> 3, j = lane & 7;
  const int pos = (c == 0) ? 0 : c*CHUNKLEN - WARM;

  // ---- fused last_T projection: xv0 = last[pos+lane][l], xv1 = last[pos+64+lane][l]
  float xv0, xv1;
  {
    const int r0 = pos + lane;
    const int r1 = min(pos + 64 + lane, 4095);   // lanes>=32 of xv1 unused; clamp OOB
    const float* p0 = x + (size_t)r0*8192 + 8128; // row r0, t=127
    const float* p1 = x + (size_t)r1*8192 + 8128;
    float a0 = b_lab[l], a1 = a0;
    #pragma unroll
    for (int k4 = 0; k4 < 16; ++k4) {
      float4 f0 = *(const float4*)(p0 + k4*4);
      float4 f1 = *(const float4*)(p1 + k4*4);
      const float* wl = W_lab + k4*256 + l;      // uniform -> scalar loads
      float w0 = wl[0], w1 = wl[64], w2 = wl[128], w3 = wl[192];
      a0 = fmaf(f0.x, w0, a0); a1 = fmaf(f1.x, w0, a1);
      a0 = fmaf(f0.y, w1, a0); a1 = fmaf(f1.y, w1, a1);
      a0 = fmaf(f0.z, w2, a0); a1 = fmaf(f1.z, w2, a1);
      a0 = fmaf(f0.w, w3, a0); a1 = fmaf(f1.w, w3, a1);
    }
    xv0 = a0; xv1 = a1;
  }

  const float LOG2E = 1.4426950408889634f;
  const float c_rz = -LOG2E;          // sigmoid: 1/(1+exp2(-log2e*s))
  const float c_n  = 2.0f*LOG2E;      // tanh:    1-2/(1+exp2(2*log2e*t))

  const float* Whh = W_hh + l*192;
  const float* Wih = W_ih + l*24;
  const float* bih = b_ih + l*24;
  const float* bhh = b_hh + l*24;

  const float wr  = c_rz * Whh[(0 +u)*8 + j];
  const float wz  = c_rz * Whh[(8 +u)*8 + j];
  const float wn  = c_n  * Whh[(16+u)*8 + j];
  const float wir = c_rz * Wih[u],      br = c_rz*(bih[u]    + bhh[u]);
  const float wiz = c_rz * Wih[8+u],    bz = c_rz*(bih[8+u]  + bhh[8+u]);
  const float win = c_n  * Wih[16+u],   bn = c_n * bih[16+u];
  const float bhn = c_n  * bhh[16+u];

  const int tr_addr = (((j << 3) | u) << 2);  // transpose: lane u*8+j <- lane j*8+u

  float hu = 0.0f;   // h[u], replicated over j
  float hj = 0.0f;   // h[j], replicated over u

  auto STEP = [&](float xt) {
    float pr = wr*hj, pz = wz*hj, pn = wn*hj;
    reduceJ(pr); reduceJ(pz); reduceJ(pn);
    float gr = fmaf(xt, wir, br);
    float gz = fmaf(xt, wiz, bz);
    float gn = fmaf(xt, win, bn);
    float r  = f_rcp(1.0f + f_exp2(pr + gr));
    float z  = f_rcp(1.0f + f_exp2(pz + gz));
    float t2 = fmaf(r, pn + bhn, gn);
    float n  = fmaf(-2.0f, f_rcp(1.0f + f_exp2(t2)), 1.0f);
    hu = fmaf(z, hu - n, n);            // (1-z)n + z*h_old[u]
    hj = __uint_as_float((unsigned)__builtin_amdgcn_ds_bpermute(
             tr_addr, (int)__float_as_uint(hu)));
  };

  float* fbase = feat + l*8 + u;
  const bool c0 = (c == 0);

  // seg 0: steps 0..31 (warm for c>0, live for c==0)
  #pragma unroll 4
  for (int t = 0; t < 32; t += 2) {
    float xa = bcast_lane(xv0, t), xb = bcast_lane(xv0, t + 1);
    STEP(xa); float h0 = hu; STEP(xb);
    if (c0 && j < 2) fbase[(size_t)(pos + t + j)*512] = (j == 0) ? h0 : hu;
  }
  // seg 1: steps 32..63 (always live)
  #pragma unroll 4
  for (int t = 32; t < 64; t += 2) {
    float xa = bcast_lane(xv0, t), xb = bcast_lane(xv0, t + 1);
    STEP(xa); float h0 = hu; STEP(xb);
    if (j < 2) fbase[(size_t)(pos + t + j)*512] = (j == 0) ? h0 : hu;
  }
  // seg 2: steps 64..95 (live for c>0 only)
  if (!c0) {
    #pragma unroll 4
    for (int t = 0; t < 32; t += 2) {
      float xa = bcast_lane(xv1, t), xb = bcast_lane(xv1, t + 1);
      STEP(xa); float h0 = hu; STEP(xb);
      if (j < 2) fbase[(size_t)(pos + 64 + t + j)*512] = (j == 0) ? h0 : hu;
    }
  }
}

// ---------------- kernel 2: output GEMM ----------------
__global__ __launch_bounds__(256) void out_kernel(
    const float* __restrict__ statik, // [4096][16]
    const float* __restrict__ W_demo, // [16][32]
    const float* __restrict__ b_demo, // [32]
    const float* __restrict__ W_out,  // [544][32]
    const float* __restrict__ b_out,  // [32]
    const float* __restrict__ feat,   // [4096][512]
    float* __restrict__ out)          // [4096][32]
{
  __shared__ float demo_s[8][33];
  const int o  = threadIdx.x & 31;
  const int bl = threadIdx.x >> 5;
  const int b  = blockIdx.x * 8 + bl;

  float d = b_demo[o];
  const float* sb = statik + (size_t)b*16;
  #pragma unroll
  for (int q = 0; q < 16; ++q) d = fmaf(sb[q], W_demo[q*32 + o], d);
  demo_s[bl][o] = d;
  __syncthreads();

  float acc = b_out[o];
  #pragma unroll
  for (int m = 0; m < 32; ++m) acc = fmaf(demo_s[bl][m], W_out[m*32 + o], acc);

  const float* fb = feat + (size_t)b*512;
  const float* Wf = W_out + 1024 + o;
  for (int k = 0; k < 512; k += 8) {
    float4 f0 = *(const float4*)(fb + k);
    float4 f1 = *(const float4*)(fb + k + 4);
    acc = fmaf(f0.x, Wf[(k+0)*32], acc);
    acc = fmaf(f0.y, Wf[(k+1)*32], acc);
    acc = fmaf(f0.z, Wf[(k+2)*32], acc);
    acc = fmaf(f0.w, Wf[(k+3)*32], acc);
    acc = fmaf(f1.x, Wf[(k+4)*32], acc);
    acc = fmaf(f1.y, Wf[(k+5)*32], acc);
    acc = fmaf(f1.z, Wf[(k+6)*32], acc);
    acc = fmaf(f1.w, Wf[(k+7)*32], acc);
  }
  out[(size_t)b*32 + o] = acc;
}

extern "C" void kernel_launch(void* const* d_in, const int* in_sizes, int n_in,
                              void* d_out, int out_size, void* d_ws, size_t ws_size,
                              hipStream_t stream) {
  const float* x      = (const float*)d_in[0];
  const float* statik = (const float*)d_in[1];
  const float* W_demo = (const float*)d_in[2];
  const float* b_demo = (const float*)d_in[3];
  const float* W_lab  = (const float*)d_in[4];
  const float* b_lab  = (const float*)d_in[5];
  const float* W_ih   = (const float*)d_in[6];
  const float* W_hh   = (const float*)d_in[7];
  const float* b_ih   = (const float*)d_in[8];
  const float* b_hh   = (const float*)d_in[9];
  const float* W_out  = (const float*)d_in[10];
  const float* b_out  = (const float*)d_in[11];
  float* out = (float*)d_out;

  float* feat = (float*)d_ws;     // 4096*512*4 = 8,388,608 B

  (void)in_sizes; (void)n_in; (void)out_size; (void)ws_size;

  gru_kernel<<<64*NCHUNK/4, 256, 0, stream>>>(x, W_lab, b_lab,
                                              W_ih, W_hh, b_ih, b_hh, feat);
  out_kernel<<<512,         256, 0, stream>>>(statik, W_demo, b_demo,
                                              W_out, b_out, feat, out);
}

// Round 5
// 47.842 us; speedup vs baseline: 2.6499x; 1.3716x over previous
//
#include <hip/hip_runtime.h>

// MCGRU: 64 independent hidden-8 GRUs scanned over the batch axis (4096 steps).
// Round-5 decomposition: 8 lanes per GRU (8 GRUs/wave), lane q owns h[q].
// Gate matvec = in-register transpose-reduce butterfly (xor1,xor2 quad_perm +
// xor7 row_half_mirror DPP): s_rel at lane q accumulates dest q^rel; after the
// 3 stages s0 = sum_k W[q][k] h[k]. No LDS, no bpermute, h stays lane-local.
// Chunked: 128 chunks x 32 live + 32-step contraction warm-in (S=64).
// x broadcast: all 8 lanes of a group load the same 32B of lastT (L1 bcast).

#define TSTRIDE  4112   // floats; 4112*4 bytes = 16B-aligned row stride
#define NCHUNK   128
#define CHLEN    32
#define WARM     32

__device__ __forceinline__ float f_exp2(float x){ return __builtin_amdgcn_exp2f(x); }
__device__ __forceinline__ float f_rcp (float x){ return __builtin_amdgcn_rcpf(x); }

template<int CTRL>
__device__ __forceinline__ float dpp_mov(float v){
  return __int_as_float(__builtin_amdgcn_update_dpp(0, __float_as_int(v), CTRL, 0xF, 0xF, true));
}

// ---------------- kernel 1: last_T ----------------
__global__ __launch_bounds__(256) void lastT_kernel(
    const float* __restrict__ x,      // [4096][128][64]
    const float* __restrict__ W_lab,  // [64][64]
    const float* __restrict__ b_lab,  // [64]
    float* __restrict__ lastT)        // [64][TSTRIDE]
{
  const int lane = threadIdx.x & 63;
  const int w    = __builtin_amdgcn_readfirstlane(threadIdx.x >> 6);
  const int b    = blockIdx.x * 64 + lane;
  float xv[64];
  const float4* xr = (const float4*)(x + ((size_t)b*128 + 127)*64);
  #pragma unroll
  for (int i = 0; i < 16; ++i) ((float4*)xv)[i] = xr[i];
  for (int li = 0; li < 16; ++li) {
    const int l = w*16 + li;            // wave-uniform -> scalar W loads
    float acc = b_lab[l];
    #pragma unroll
    for (int k = 0; k < 64; ++k)
      acc = fmaf(xv[k], W_lab[k*64 + l], acc);
    lastT[l*TSTRIDE + b] = acc;
  }
}

// ---------------- kernel 2: GRU scan (8 GRUs per wave) ----------------
__global__ __launch_bounds__(256) void gru_kernel(
    const float* __restrict__ lastT,  // [64][TSTRIDE]
    const float* __restrict__ W_ih,   // [64][24]
    const float* __restrict__ W_hh,   // [64][24][8]
    const float* __restrict__ b_ih,   // [64][24]
    const float* __restrict__ b_hh,   // [64][24]
    float* __restrict__ feat)         // [4096][512]
{
  const int tid  = threadIdx.x;
  const int lane = tid & 63;
  const int wv   = tid >> 6;               // wave 0..3
  const int g    = lane >> 3, q = lane & 7;
  const int lab  = ((blockIdx.x & 7) << 3) + g;        // this group's GRU
  const int c    = ((blockIdx.x >> 3) << 2) + wv;      // chunk 0..127 (wave-uniform)
  const int pos  = (c == 0) ? 0 : c*CHLEN - WARM;
  const int nblk = (c == 0) ? CHLEN/8 : (CHLEN+WARM)/8;
  const int tlive= (c == 0) ? 0 : WARM;

  const float LOG2E = 1.4426950408889634f;
  const float c_rz = -LOG2E;          // sigmoid: 1/(1+exp2(-log2e*s))
  const float c_n  = 2.0f*LOG2E;      // tanh:    1-2/(1+exp2(2*log2e*t))

  const float* Whh = W_hh + lab*192;
  const float* Wih = W_ih + lab*24;
  const float* bih = b_ih + lab*24;
  const float* bhh = b_hh + lab*24;

  // butterfly weights: w*[rel] at lane q = c * W[(q^rel)][q]
  float wr[8], wz[8], wn[8];
  #pragma unroll
  for (int rel = 0; rel < 8; ++rel) {
    const int dr = q ^ rel;
    wr[rel] = c_rz * Whh[(0  + dr)*8 + q];
    wz[rel] = c_rz * Whh[(8  + dr)*8 + q];
    wn[rel] = c_n  * Whh[(16 + dr)*8 + q];
  }
  const float wir = c_rz * Wih[q],     br = c_rz*(bih[q]    + bhh[q]);
  const float wiz = c_rz * Wih[8+q],   bz = c_rz*(bih[8+q]  + bhh[8+q]);
  const float win = c_n  * Wih[16+q],  bn = c_n * bih[16+q];
  const float bhn = c_n  * bhh[16+q];

  // transpose-reduce: returns sum_k W[q][k]*h[k] at every lane (dest = own q)
  auto TREE = [&](const float* w, float h)->float {
    float s0 = w[0]*h, s1 = w[1]*h, s2 = w[2]*h, s3 = w[3]*h;
    float s4 = w[4]*h, s5 = w[5]*h, s6 = w[6]*h, s7 = w[7]*h;
    s0 += dpp_mov<0xB1>(s1);   // xor1: partner's s1 holds dest q
    s2 += dpp_mov<0xB1>(s3);
    s5 += dpp_mov<0xB1>(s4);
    s7 += dpp_mov<0xB1>(s6);
    s0 += dpp_mov<0x4E>(s2);   // xor2
    s7 += dpp_mov<0x4E>(s5);
    s0 += dpp_mov<0x141>(s7);  // xor7 (row_half_mirror)
    return s0;
  };

  const float* xrow = lastT + (size_t)lab*TSTRIDE + pos;  // 16B-aligned
  float4 xlo = *(const float4*)(xrow);
  float4 xhi = *(const float4*)(xrow + 4);

  float h = 0.0f;
  float* fcol = feat + ((blockIdx.x & 7) << 6) + lane;    // col = lab*8+q

  for (int blk = 0; blk < nblk; ++blk) {
    const int nb = min(blk + 1, nblk - 1);
    float4 nlo = *(const float4*)(xrow + nb*8);           // prefetch next block
    float4 nhi = *(const float4*)(xrow + nb*8 + 4);
    const float xb[8] = {xlo.x,xlo.y,xlo.z,xlo.w, xhi.x,xhi.y,xhi.z,xhi.w};
    #pragma unroll
    for (int i = 0; i < 8; ++i) {
      const float xt = xb[i];
      float pr = TREE(wr, h);
      float pz = TREE(wz, h);
      float pn = TREE(wn, h);
      float gr = fmaf(xt, wir, br);
      float gz = fmaf(xt, wiz, bz);
      float gn = fmaf(xt, win, bn);
      float r  = f_rcp(1.0f + f_exp2(pr + gr));
      float z  = f_rcp(1.0f + f_exp2(pz + gz));
      float t2 = fmaf(r, pn + bhn, gn);
      float n  = fmaf(-2.0f, f_rcp(1.0f + f_exp2(t2)), 1.0f);
      h = fmaf(z, h - n, n);              // (1-z)n + z*h_old[q]
      const int t = blk*8 + i;
      if (t >= tlive)                     // wave-uniform branch
        fcol[(size_t)(pos + t)*512] = h;  // coalesced 256B/store
    }
    xlo = nlo; xhi = nhi;
  }
}

// ---------------- kernel 3: output GEMM ----------------
__global__ __launch_bounds__(256) void out_kernel(
    const float* __restrict__ statik, // [4096][16]
    const float* __restrict__ W_demo, // [16][32]
    const float* __restrict__ b_demo, // [32]
    const float* __restrict__ W_out,  // [544][32]
    const float* __restrict__ b_out,  // [32]
    const float* __restrict__ feat,   // [4096][512]
    float* __restrict__ out)          // [4096][32]
{
  __shared__ float demo_s[8][33];
  const int o  = threadIdx.x & 31;
  const int bl = threadIdx.x >> 5;
  const int b  = blockIdx.x * 8 + bl;

  float d = b_demo[o];
  const float* sb = statik + (size_t)b*16;
  #pragma unroll
  for (int qq = 0; qq < 16; ++qq) d = fmaf(sb[qq], W_demo[qq*32 + o], d);
  demo_s[bl][o] = d;
  __syncthreads();

  float acc = b_out[o];
  #pragma unroll
  for (int m = 0; m < 32; ++m) acc = fmaf(demo_s[bl][m], W_out[m*32 + o], acc);

  const float* fb = feat + (size_t)b*512;
  const float* Wf = W_out + 1024 + o;
  for (int k = 0; k < 512; k += 8) {
    float4 f0 = *(const float4*)(fb + k);
    float4 f1 = *(const float4*)(fb + k + 4);
    acc = fmaf(f0.x, Wf[(k+0)*32], acc);
    acc = fmaf(f0.y, Wf[(k+1)*32], acc);
    acc = fmaf(f0.z, Wf[(k+2)*32], acc);
    acc = fmaf(f0.w, Wf[(k+3)*32], acc);
    acc = fmaf(f1.x, Wf[(k+4)*32], acc);
    acc = fmaf(f1.y, Wf[(k+5)*32], acc);
    acc = fmaf(f1.z, Wf[(k+6)*32], acc);
    acc = fmaf(f1.w, Wf[(k+7)*32], acc);
  }
  out[(size_t)b*32 + o] = acc;
}

extern "C" void kernel_launch(void* const* d_in, const int* in_sizes, int n_in,
                              void* d_out, int out_size, void* d_ws, size_t ws_size,
                              hipStream_t stream) {
  const float* x      = (const float*)d_in[0];
  const float* statik = (const float*)d_in[1];
  const float* W_demo = (const float*)d_in[2];
  const float* b_demo = (const float*)d_in[3];
  const float* W_lab  = (const float*)d_in[4];
  const float* b_lab  = (const float*)d_in[5];
  const float* W_ih   = (const float*)d_in[6];
  const float* W_hh   = (const float*)d_in[7];
  const float* b_ih   = (const float*)d_in[8];
  const float* b_hh   = (const float*)d_in[9];
  const float* W_out  = (const float*)d_in[10];
  const float* b_out  = (const float*)d_in[11];
  float* out = (float*)d_out;

  float* lastT = (float*)d_ws;                                 // 64*4112*4 B
  float* feat  = (float*)((char*)d_ws + (size_t)64*TSTRIDE*4); // 4096*512*4 B

  (void)in_sizes; (void)n_in; (void)out_size; (void)ws_size;

  lastT_kernel<<<64,  256, 0, stream>>>(x, W_lab, b_lab, lastT);
  gru_kernel  <<<256, 256, 0, stream>>>(lastT, W_ih, W_hh, b_ih, b_hh, feat);
  out_kernel  <<<512, 256, 0, stream>>>(statik, W_demo, b_demo, W_out, b_out, feat, out);
}